// Round 4
// baseline (1324.375 us; speedup 1.0000x reference)
//
#include <hip/hip_runtime.h>
#include <stdint.h>

#define D_DIM 2048
#define K_DIM 64
#define T_DIM 2048
#define BT_DIM 16384   // B*T = 8*2048

typedef __attribute__((address_space(3))) uint32_t lds_u32;
typedef const __attribute__((address_space(1))) uint32_t glob_u32;

// ---------------------------------------------------------------------------
// Kernel A: softmax over k of w[d,:], stored PACKED for the gemm:
//   pC[(d>>2)*256 + k*4 + (d&3)] = softmax(w[d,:])[k]
// ---------------------------------------------------------------------------
__global__ __launch_bounds__(256) void softmax_k(const float* __restrict__ w,
                                                 float* __restrict__ pC) {
    const int lane = threadIdx.x & 63;
    const int d = blockIdx.x * 4 + (threadIdx.x >> 6);
    float v = w[d * K_DIM + lane];
    float m = v;
#pragma unroll
    for (int off = 32; off > 0; off >>= 1) m = fmaxf(m, __shfl_xor(m, off, 64));
    float e = expf(v - m);
    float s = e;
#pragma unroll
    for (int off = 32; off > 0; off >>= 1) s += __shfl_xor(s, off, 64);
    pC[(d >> 2) * 256 + lane * 4 + (d & 3)] = e / s;
}

// ---------------------------------------------------------------------------
// Kernel B: per-column min/max of w -> nT[k,d] = (w[d,k]-mn)/(mx-mn).
// ---------------------------------------------------------------------------
__global__ __launch_bounds__(256) void norm_k(const float* __restrict__ w,
                                              float* __restrict__ nT) {
    const int k = blockIdx.x;
    const int lane = threadIdx.x & 63;
    const int wave = threadIdx.x >> 6;
    float mn = 1e30f, mx = -1e30f;
    for (int d = threadIdx.x; d < D_DIM; d += 256) {
        float v = w[d * K_DIM + k];
        mn = fminf(mn, v);
        mx = fmaxf(mx, v);
    }
#pragma unroll
    for (int off = 32; off > 0; off >>= 1) {
        mn = fminf(mn, __shfl_xor(mn, off, 64));
        mx = fmaxf(mx, __shfl_xor(mx, off, 64));
    }
    __shared__ float red[8];
    if (lane == 0) { red[wave] = mn; red[4 + wave] = mx; }
    __syncthreads();
    mn = fminf(fminf(red[0], red[1]), fminf(red[2], red[3]));
    mx = fmaxf(fmaxf(red[4], red[5]), fmaxf(red[6], red[7]));
    const float inv = 1.0f / (mx - mn);
    for (int d = threadIdx.x; d < D_DIM; d += 256) {
        nT[k * D_DIM + d] = (w[d * K_DIM + k] - mn) * inv;
    }
}

// ---------------------------------------------------------------------------
// Kernel C1: scores = X @ P (fp32 VALU) -> per-row (argmax, sign).
// v5 = v4 register tiling (32 rows, 4 waves = d-quarters, acc[8][4]/lane)
//   + double-buffered x staging with COUNTED vmcnt (per-wave private, no
//     barriers): stage(it+1) issues at top of it; s_waitcnt vmcnt(12) waits
//     only tile it (12 = pv(it,0) 4 + stage(it+1) 8 younger ops; vmcnt
//     retires in order). Steady-state stall ~0.
//   + pv (packed p from L2) double-buffered across chunks: chunk c
//     prefetches c+1 (pvA/pvB, compile-time parity under full unroll).
// FMA accumulation order is UNCHANGED from the passing v4 -> stats
// bit-identical -> absmax unchanged.
// ---------------------------------------------------------------------------
#define CHUNK_BODY(USE, PRE)                                                   \
    {                                                                          \
        if (doPre) {                                                           \
            PRE[0] = *(const float4*)(nx + 0);                                 \
            PRE[1] = *(const float4*)(nx + 4);                                 \
            PRE[2] = *(const float4*)(nx + 8);                                 \
            PRE[3] = *(const float4*)(nx + 12);                                \
        }                                                                      \
        _Pragma("unroll")                                                      \
        for (int rr = 0; rr < 8; ++rr) {                                       \
            const int row = rg * 8 + rr;                                       \
            const float4 xv = *(const float4*)(cur + row * 64 + ((c ^ rg) << 2)); \
            _Pragma("unroll")                                                  \
            for (int kk = 0; kk < 4; ++kk) {                                   \
                float a = acc[rr][kk];                                         \
                a = fmaf(xv.x, USE[kk].x, a);                                  \
                a = fmaf(xv.y, USE[kk].y, a);                                  \
                a = fmaf(xv.z, USE[kk].z, a);                                  \
                a = fmaf(xv.w, USE[kk].w, a);                                  \
                acc[rr][kk] = a;                                               \
            }                                                                  \
        }                                                                      \
    }

__global__ __launch_bounds__(256, 2) void gemm_stats_k(const float* __restrict__ x,
                                                       const float* __restrict__ pC,
                                                       int* __restrict__ stats) {
    const int lane = threadIdx.x & 63;
    const int wave = threadIdx.x >> 6;
    const int r0 = blockIdx.x * 32;
    const int dw0 = wave * (D_DIM / 4);            // this wave's d-quarter
    const int rg = lane >> 4;                      // 0..3: rows rg*8..rg*8+7
    const int kg = lane & 15;                      // k = kg*4 + kk

    __shared__ float xs_all[4][2][32 * 64];        // 64 KB: per-wave double buffer
    float* cur = &xs_all[wave][0][0];
    float* nxt = &xs_all[wave][1][0];

    float acc[8][4];
#pragma unroll
    for (int rr = 0; rr < 8; ++rr)
#pragma unroll
        for (int kk = 0; kk < 4; ++kk) acc[rr][kk] = 0.0f;

    const float* __restrict__ xg = x + (size_t)r0 * D_DIM + dw0;   // wave x panel
    const float* __restrict__ pgBase = pC + (size_t)(wave * 128) * 256 + kg * 16;

    const int srow = lane >> 4;                    // staging row within group of 4
    const int scolBase = kg << 2;                  // pre-swizzle applied per-j below

    // ---- prologue: stage tile 0 into cur, prefetch pv(0,0) into pvA
#pragma unroll
    for (int j = 0; j < 8; ++j) {
        const int swz = (j >> 1) & 3;
        const float* src = xg + (size_t)(j * 4 + srow) * D_DIM + ((kg ^ swz) << 2);
        __builtin_amdgcn_global_load_lds((glob_u32*)src, (lds_u32*)(cur + j * 256),
                                         16, 0, 0);
    }
    float4 pvA[4], pvB[4];
#pragma unroll
    for (int kk = 0; kk < 4; ++kk) pvA[kk] = *(const float4*)(pgBase + kk * 4);

#pragma unroll 1
    for (int it = 0; it < 8; ++it) {
        // ---- [A] issue staging of tile it+1 into nxt (8 x 1KB loads)
        if (it < 7) {
#pragma unroll
            for (int j = 0; j < 8; ++j) {
                const int swz = (j >> 1) & 3;
                const float* src = xg + (size_t)(j * 4 + srow) * D_DIM
                                   + (it + 1) * 64 + ((kg ^ swz) << 2);
                __builtin_amdgcn_global_load_lds((glob_u32*)src,
                                                 (lds_u32*)(nxt + j * 256),
                                                 16, 0, 0);
            }
            // ---- [B] wait for tile it: younger = pv(it,0) 4 + stage(it+1) 8
            asm volatile("s_waitcnt vmcnt(12)" ::: "memory");
        } else {
            // younger = pv(7,0) 4 only
            asm volatile("s_waitcnt vmcnt(4)" ::: "memory");
        }

        const float* pIt = pgBase + (size_t)it * 4096;
#pragma unroll
        for (int c = 0; c < 16; ++c) {
            const bool doPre = (c < 15) || (it < 7);
            const float* nx = (c < 15) ? (pIt + (c + 1) * 256) : (pIt + 4096);
            if ((c & 1) == 0) {
                CHUNK_BODY(pvA, pvB)
            } else {
                CHUNK_BODY(pvB, pvA)
            }
        }
        float* t = cur; cur = nxt; nxt = t;
    }

    // ---- cross-wave reduction + 64-lane argmax (identical to v4) ----------
    __syncthreads();                               // all waves done with xs
    float (*red)[32][64] = reinterpret_cast<float (*)[32][64]>(&xs_all[0][0][0]);
#pragma unroll
    for (int rr = 0; rr < 8; ++rr)
#pragma unroll
        for (int kk = 0; kk < 4; ++kk)
            red[wave][rg * 8 + rr][kg * 4 + kk] = acc[rr][kk];
    __syncthreads();

#pragma unroll
    for (int rr = 0; rr < 8; ++rr) {
        const int r = wave * 8 + rr;
        float v = red[0][r][lane] + red[1][r][lane] + red[2][r][lane] + red[3][r][lane];
        int idx = lane;
#pragma unroll
        for (int off = 32; off > 0; off >>= 1) {
            const float ov = __shfl_xor(v, off, 64);
            const int oi = __shfl_xor(idx, off, 64);
            if (ov > v || (ov == v && oi < idx)) { v = ov; idx = oi; }
        }
        if (lane == 0) stats[r0 + r] = idx | ((v < 0.0f) ? (1 << 8) : 0);
    }
}

// ---------------------------------------------------------------------------
// Kernel C2: out[r,d] = x[r,d] * (1 + W), W from stats[r-1]; rows t==0: W=0.
// 8 rows per block (grid 2048).
// ---------------------------------------------------------------------------
__global__ __launch_bounds__(256) void output_k(const float* __restrict__ x,
                                                const float* __restrict__ nT,
                                                const int* __restrict__ stats,
                                                float* __restrict__ out) {
    const int tid = threadIdx.x;
#pragma unroll 1
    for (int rr = 0; rr < 8; ++rr) {
        const int row = blockIdx.x * 8 + rr;
        const int t = row & (T_DIM - 1);
        const float4* x4 = (const float4*)(x + (size_t)row * D_DIM);
        float4* o4 = (float4*)(out + (size_t)row * D_DIM);
        if (t == 0) {
#pragma unroll
            for (int it = 0; it < 2; ++it) {
                const int i = tid + it * 256;
                o4[i] = x4[i];
            }
            continue;
        }
        const int s = stats[row - 1];
        const int ind = s & 0xff;
        const bool neg = (s >> 8) & 1;
        const float4* n4 = (const float4*)(nT + (size_t)ind * D_DIM);
#pragma unroll
        for (int it = 0; it < 2; ++it) {
            const int i = tid + it * 256;
            const float4 xv = x4[i];
            const float4 nv = n4[i];
            float4 r;
            const float w0 = neg ? 1.0f - nv.x : nv.x;
            const float w1 = neg ? 1.0f - nv.y : nv.y;
            const float w2 = neg ? 1.0f - nv.z : nv.z;
            const float w3 = neg ? 1.0f - nv.w : nv.w;
            r.x = fmaf(xv.x, w0, xv.x);
            r.y = fmaf(xv.y, w1, xv.y);
            r.z = fmaf(xv.z, w2, xv.z);
            r.w = fmaf(xv.w, w3, xv.w);
            o4[i] = r;
        }
    }
}

extern "C" void kernel_launch(void* const* d_in, const int* in_sizes, int n_in,
                              void* d_out, int out_size, void* d_ws, size_t ws_size,
                              hipStream_t stream) {
    const float* x = (const float*)d_in[0];   // [B,T,D] fp32
    const float* w = (const float*)d_in[1];   // [D,K] fp32
    float* out = (float*)d_out;

    float* pC = (float*)d_ws;                 // [D/4][K][4] packed softmax, 512 KB
    float* nT = pC + (size_t)K_DIM * D_DIM;   // [K,D]  512 KB
    int* stats = (int*)(nT + (size_t)K_DIM * D_DIM);  // [B*T] 64 KB

    softmax_k<<<D_DIM / 4, 256, 0, stream>>>(w, pC);
    norm_k<<<K_DIM, 256, 0, stream>>>(w, nT);
    gemm_stats_k<<<BT_DIM / 32, 256, 0, stream>>>(x, pC, stats);
    output_k<<<BT_DIM / 8, 256, 0, stream>>>(x, nT, stats, out);
}

// Round 6
// 308.045 us; speedup vs baseline: 4.2993x; 4.2993x over previous
//
#include <hip/hip_runtime.h>
#include <stdint.h>

#define D_DIM 2048
#define K_DIM 64
#define T_DIM 2048
#define BT_DIM 16384   // B*T = 8*2048

typedef __attribute__((address_space(3))) uint32_t lds_u32;
typedef const __attribute__((address_space(1))) uint32_t glob_u32;

// ---------------------------------------------------------------------------
// Kernel A: softmax over k of w[d,:], stored PACKED for the gemm:
//   pC[(d>>2)*256 + k*4 + (d&3)] = softmax(w[d,:])[k]
// ---------------------------------------------------------------------------
__global__ __launch_bounds__(256) void softmax_k(const float* __restrict__ w,
                                                 float* __restrict__ pC) {
    const int lane = threadIdx.x & 63;
    const int d = blockIdx.x * 4 + (threadIdx.x >> 6);
    float v = w[d * K_DIM + lane];
    float m = v;
#pragma unroll
    for (int off = 32; off > 0; off >>= 1) m = fmaxf(m, __shfl_xor(m, off, 64));
    float e = expf(v - m);
    float s = e;
#pragma unroll
    for (int off = 32; off > 0; off >>= 1) s += __shfl_xor(s, off, 64);
    pC[(d >> 2) * 256 + lane * 4 + (d & 3)] = e / s;
}

// ---------------------------------------------------------------------------
// Kernel B: per-column min/max of w -> nT[k,d] = (w[d,k]-mn)/(mx-mn).
// ---------------------------------------------------------------------------
__global__ __launch_bounds__(256) void norm_k(const float* __restrict__ w,
                                              float* __restrict__ nT) {
    const int k = blockIdx.x;
    const int lane = threadIdx.x & 63;
    const int wave = threadIdx.x >> 6;
    float mn = 1e30f, mx = -1e30f;
    for (int d = threadIdx.x; d < D_DIM; d += 256) {
        float v = w[d * K_DIM + k];
        mn = fminf(mn, v);
        mx = fmaxf(mx, v);
    }
#pragma unroll
    for (int off = 32; off > 0; off >>= 1) {
        mn = fminf(mn, __shfl_xor(mn, off, 64));
        mx = fmaxf(mx, __shfl_xor(mx, off, 64));
    }
    __shared__ float red[8];
    if (lane == 0) { red[wave] = mn; red[4 + wave] = mx; }
    __syncthreads();
    mn = fminf(fminf(red[0], red[1]), fminf(red[2], red[3]));
    mx = fmaxf(fmaxf(red[4], red[5]), fmaxf(red[6], red[7]));
    const float inv = 1.0f / (mx - mn);
    for (int d = threadIdx.x; d < D_DIM; d += 256) {
        nT[k * D_DIM + d] = (w[d * K_DIM + k] - mn) * inv;
    }
}

// ---------------------------------------------------------------------------
// Kernel C1: scores = X @ P (fp32 VALU) -> per-row (argmax, sign).
// v6 = v4 (proven 106us, 92 VGPR) + x-tile DOUBLE BUFFER with counted vmcnt,
// and NOTHING else (R2/R4 showed >=32 extra regs of prefetch state = spill).
//  - stage(it+1) issues into the alternate per-wave LDS buffer at top of it,
//    then s_waitcnt vmcnt(8): only the 8 just-issued loads may remain
//    outstanding -> waits exactly for tile it (issued a full iteration ago,
//    ~free in steady state). In-order vmem retirement makes the count exact;
//    the "memory" clobber pins compiler pv loads behind the wait.
//  - pv loads stay just-in-time inside the unrolled chunk loop, as in v4.
//  - FMA accumulation order UNCHANGED from v4 -> stats bit-identical.
// ---------------------------------------------------------------------------
__global__ __launch_bounds__(256, 2) void gemm_stats_k(const float* __restrict__ x,
                                                       const float* __restrict__ pC,
                                                       int* __restrict__ stats) {
    const int lane = threadIdx.x & 63;
    const int wave = threadIdx.x >> 6;
    const int r0 = blockIdx.x * 32;
    const int dw0 = wave * (D_DIM / 4);            // this wave's d-quarter
    const int rg = lane >> 4;                      // 0..3: rows rg*8..rg*8+7
    const int kg = lane & 15;                      // k = kg*4 + kk

    __shared__ float xs_all[4][2][32 * 64];        // 64 KB: per-wave double buffer
    float* cur = &xs_all[wave][0][0];
    float* nxt = &xs_all[wave][1][0];

    float acc[8][4];
#pragma unroll
    for (int rr = 0; rr < 8; ++rr)
#pragma unroll
        for (int kk = 0; kk < 4; ++kk) acc[rr][kk] = 0.0f;

    const float* __restrict__ xg = x + (size_t)r0 * D_DIM + dw0;   // wave x panel
    const float* __restrict__ pgBase = pC + (size_t)(wave * 128) * 256 + kg * 16;

    const int srow = lane >> 4;                    // staging row within group of 4

    // ---- prologue: stage tile 0 into cur
#pragma unroll
    for (int j = 0; j < 8; ++j) {
        const int swz = (j >> 1) & 3;
        const float* src = xg + (size_t)(j * 4 + srow) * D_DIM + ((kg ^ swz) << 2);
        __builtin_amdgcn_global_load_lds((glob_u32*)src, (lds_u32*)(cur + j * 256),
                                         16, 0, 0);
    }

#pragma unroll 1
    for (int it = 0; it < 8; ++it) {
        // ---- issue staging of tile it+1 into nxt, then wait ONLY for tile it
        if (it < 7) {
#pragma unroll
            for (int j = 0; j < 8; ++j) {
                const int swz = (j >> 1) & 3;
                const float* src = xg + (size_t)(j * 4 + srow) * D_DIM
                                   + (it + 1) * 64 + ((kg ^ swz) << 2);
                __builtin_amdgcn_global_load_lds((glob_u32*)src,
                                                 (lds_u32*)(nxt + j * 256),
                                                 16, 0, 0);
            }
            asm volatile("s_waitcnt vmcnt(8)" ::: "memory");
        } else {
            asm volatile("s_waitcnt vmcnt(0)" ::: "memory");
        }

        // ---- compute: 16 sub-chunks of 4 d (identical to v4)
#pragma unroll
        for (int c = 0; c < 16; ++c) {
            const float* pcc = pgBase + (size_t)(it * 16 + c) * 256;
            float4 pv[4];
#pragma unroll
            for (int kk = 0; kk < 4; ++kk)
                pv[kk] = *(const float4*)(pcc + kk * 4);
#pragma unroll
            for (int rr = 0; rr < 8; ++rr) {
                const int row = rg * 8 + rr;
                const float4 xv = *(const float4*)(cur + row * 64 + ((c ^ rg) << 2));
#pragma unroll
                for (int kk = 0; kk < 4; ++kk) {
                    float a = acc[rr][kk];
                    a = fmaf(xv.x, pv[kk].x, a);
                    a = fmaf(xv.y, pv[kk].y, a);
                    a = fmaf(xv.z, pv[kk].z, a);
                    a = fmaf(xv.w, pv[kk].w, a);
                    acc[rr][kk] = a;
                }
            }
        }
        float* t = cur; cur = nxt; nxt = t;
    }

    // ---- cross-wave reduction + 64-lane argmax (identical to v4) ----------
    __syncthreads();                               // all waves done with xs
    float (*red)[32][64] = reinterpret_cast<float (*)[32][64]>(&xs_all[0][0][0]);
#pragma unroll
    for (int rr = 0; rr < 8; ++rr)
#pragma unroll
        for (int kk = 0; kk < 4; ++kk)
            red[wave][rg * 8 + rr][kg * 4 + kk] = acc[rr][kk];
    __syncthreads();

#pragma unroll
    for (int rr = 0; rr < 8; ++rr) {
        const int r = wave * 8 + rr;
        float v = red[0][r][lane] + red[1][r][lane] + red[2][r][lane] + red[3][r][lane];
        int idx = lane;
#pragma unroll
        for (int off = 32; off > 0; off >>= 1) {
            const float ov = __shfl_xor(v, off, 64);
            const int oi = __shfl_xor(idx, off, 64);
            if (ov > v || (ov == v && oi < idx)) { v = ov; idx = oi; }
        }
        if (lane == 0) stats[r0 + r] = idx | ((v < 0.0f) ? (1 << 8) : 0);
    }
}

// ---------------------------------------------------------------------------
// Kernel C2: out[r,d] = x[r,d] * (1 + W), W from stats[r-1]; rows t==0: W=0.
// 8 rows per block (grid 2048).
// ---------------------------------------------------------------------------
__global__ __launch_bounds__(256) void output_k(const float* __restrict__ x,
                                                const float* __restrict__ nT,
                                                const int* __restrict__ stats,
                                                float* __restrict__ out) {
    const int tid = threadIdx.x;
#pragma unroll 1
    for (int rr = 0; rr < 8; ++rr) {
        const int row = blockIdx.x * 8 + rr;
        const int t = row & (T_DIM - 1);
        const float4* x4 = (const float4*)(x + (size_t)row * D_DIM);
        float4* o4 = (float4*)(out + (size_t)row * D_DIM);
        if (t == 0) {
#pragma unroll
            for (int it = 0; it < 2; ++it) {
                const int i = tid + it * 256;
                o4[i] = x4[i];
            }
            continue;
        }
        const int s = stats[row - 1];
        const int ind = s & 0xff;
        const bool neg = (s >> 8) & 1;
        const float4* n4 = (const float4*)(nT + (size_t)ind * D_DIM);
#pragma unroll
        for (int it = 0; it < 2; ++it) {
            const int i = tid + it * 256;
            const float4 xv = x4[i];
            const float4 nv = n4[i];
            float4 r;
            const float w0 = neg ? 1.0f - nv.x : nv.x;
            const float w1 = neg ? 1.0f - nv.y : nv.y;
            const float w2 = neg ? 1.0f - nv.z : nv.z;
            const float w3 = neg ? 1.0f - nv.w : nv.w;
            r.x = fmaf(xv.x, w0, xv.x);
            r.y = fmaf(xv.y, w1, xv.y);
            r.z = fmaf(xv.z, w2, xv.z);
            r.w = fmaf(xv.w, w3, xv.w);
            o4[i] = r;
        }
    }
}

extern "C" void kernel_launch(void* const* d_in, const int* in_sizes, int n_in,
                              void* d_out, int out_size, void* d_ws, size_t ws_size,
                              hipStream_t stream) {
    const float* x = (const float*)d_in[0];   // [B,T,D] fp32
    const float* w = (const float*)d_in[1];   // [D,K] fp32
    float* out = (float*)d_out;

    float* pC = (float*)d_ws;                 // [D/4][K][4] packed softmax, 512 KB
    float* nT = pC + (size_t)K_DIM * D_DIM;   // [K,D]  512 KB
    int* stats = (int*)(nT + (size_t)K_DIM * D_DIM);  // [B*T] 64 KB

    softmax_k<<<D_DIM / 4, 256, 0, stream>>>(w, pC);
    norm_k<<<K_DIM, 256, 0, stream>>>(w, nT);
    gemm_stats_k<<<BT_DIM / 32, 256, 0, stream>>>(x, pC, stats);
    output_k<<<BT_DIM / 8, 256, 0, stream>>>(x, nT, stats, out);
}